// Round 1
// 332.635 us; speedup vs baseline: 1.0502x; 1.0502x over previous
//
#include <hip/hip_runtime.h>
#include <hip/hip_bf16.h>

#define BATCH  16
#define CCH    128
#define TDIM   16384
#define MROWS  256                 // 2C
#define NCHUNK 16
#define KC     (TDIM / NCHUNK)     // 1024
#define BK     32
#define NSTEP  (KC / BK)           // 32
#define LDSP   40                  // padded LDS row stride (elements)
#define GRAM   (MROWS * MROWS)     // 65536

typedef __attribute__((ext_vector_type(8))) short bf16x8;
typedef __attribute__((ext_vector_type(4))) float f32x4;
typedef __attribute__((ext_vector_type(4))) unsigned short u16x4;

__device__ __forceinline__ unsigned short f2bf(float x) {
  // RTNE fp32 -> bf16 (inputs are finite normals; no NaN path needed)
  unsigned int u = __float_as_uint(x);
  u += 0x7fffu + ((u >> 16) & 1u);
  return (unsigned short)(u >> 16);
}

// Barrier WITHOUT the compiler's vmcnt(0) drain: only LDS ops must be
// visible across the barrier; global loads (register dests) need no
// cross-wave ordering. This keeps the 8 prefetch loads in flight across
// the barrier (T4: never drain vmcnt to 0 in the main loop).
__device__ __forceinline__ void pipe_barrier() {
  asm volatile("s_waitcnt lgkmcnt(0)" ::: "memory");
  __builtin_amdgcn_s_barrier();
  asm volatile("" ::: "memory");
}

__device__ __forceinline__ void load_step(
    f32x4 (&v)[4], const float* const (&rowptr)[4], int s)
{
  #pragma unroll
  for (int j = 0; j < 4; ++j)
    v[j] = *(const f32x4*)(rowptr[j] + s * BK);
}

__device__ __forceinline__ void stage_step(
    unsigned short (&buf)[MROWS][LDSP], const f32x4 (&v)[4],
    const int (&rowidx)[4], const int (&kq4)[4])
{
  #pragma unroll
  for (int j = 0; j < 4; ++j) {
    u16x4 p;
    p.x = f2bf(v[j].x); p.y = f2bf(v[j].y); p.z = f2bf(v[j].z); p.w = f2bf(v[j].w);
    *(u16x4*)&buf[rowidx[j]][kq4[j]] = p;
  }
}

__device__ __forceinline__ void compute_step(
    const unsigned short (&buf)[MROWS][LDSP],
    f32x4 (&acc)[4][8], int wr, int wc, int llo, int koff)
{
  bf16x8 af[4], bfr[8];
  #pragma unroll
  for (int i = 0; i < 4; ++i)
    af[i] = *(const bf16x8*)&buf[wr * 64 + i * 16 + llo][koff];
  #pragma unroll
  for (int j = 0; j < 8; ++j)
    bfr[j] = *(const bf16x8*)&buf[wc * 128 + j * 16 + llo][koff];
  #pragma unroll
  for (int i = 0; i < 4; ++i)
    #pragma unroll
    for (int j = 0; j < 8; ++j)
      acc[i][j] = __builtin_amdgcn_mfma_f32_16x16x32_bf16(af[i], bfr[j], acc[i][j], 0, 0, 0);
}

// Computes partial gram of M_b = [s_b; t_b] (256 x T) over one K-chunk.
// atomic_mode=0: store partial to outp + blockIdx*GRAM (64 MB ws path)
// atomic_mode=1: atomicAdd into outp + b*GRAM (4 MB ws path)
__global__ __launch_bounds__(512, 2) void gram_kernel(
    const float* __restrict__ fs, const float* __restrict__ ft,
    float* __restrict__ outp, int atomic_mode)
{
  __shared__ __attribute__((aligned(16))) unsigned short sm[2][MROWS][LDSP];

  const int tid   = threadIdx.x;
  const int bidx  = blockIdx.x;
  const int b     = bidx / NCHUNK;
  const int chunk = bidx - b * NCHUNK;
  const int kbase = chunk * KC;

  const int lane = tid & 63;
  const int w    = tid >> 6;     // wave 0..7
  const int wr   = w & 3;        // row-tile group: rows [wr*64, wr*64+64)
  const int wc   = w >> 2;       // col-tile group: cols [wc*128, wc*128+128)
  const int lhi  = lane >> 4;    // 0..3
  const int llo  = lane & 15;
  const int koff = lhi * 8;      // k offset of this lane's 8 bf16 (A/B layout)

  // staging assignment: idx = j*512+tid -> row = idx>>3, 8 float4 per row
  const float* rowptr[4];
  int rowidx[4], kq4[4];
  #pragma unroll
  for (int j = 0; j < 4; ++j) {
    int idx = j * 512 + tid;
    int row = idx >> 3;
    int kq  = idx & 7;
    rowidx[j] = row;
    kq4[j]    = kq * 4;
    const float* base = (row < CCH)
        ? (fs + (size_t)(b * CCH + row) * TDIM)
        : (ft + (size_t)(b * CCH + (row - CCH)) * TDIM);
    rowptr[j] = base + kbase + kq * 4;
  }

  f32x4 acc[4][8];
  #pragma unroll
  for (int i = 0; i < 4; ++i)
    #pragma unroll
    for (int j = 0; j < 8; ++j)
      acc[i][j] = (f32x4){0.f, 0.f, 0.f, 0.f};

  // -------- depth-2 software pipeline --------
  // Named register buffers va/vb (static indexing only — rule #20).
  // At step i we prefetch step i+2 and stage step i+1's registers, so
  // every load has ~2 full compute phases to land before its vmcnt wait.
  f32x4 va[4], vb[4];
  load_step(va, rowptr, 0);
  load_step(vb, rowptr, 1);
  stage_step(sm[0], va, rowidx, kq4);   // compiler waits va only (vmcnt counted)
  pipe_barrier();

  #pragma unroll 1
  for (int s = 0; s < NSTEP - 2; s += 2) {
    // even step s: compute sm[0], stage vb(=step s+1)->sm[1], prefetch va=step s+2
    load_step(va, rowptr, s + 2);
    compute_step(sm[0], acc, wr, wc, llo, koff);
    stage_step(sm[1], vb, rowidx, kq4);
    pipe_barrier();
    // odd step s+1: compute sm[1], stage va(=step s+2)->sm[0], prefetch vb=step s+3
    load_step(vb, rowptr, s + 3);
    compute_step(sm[1], acc, wr, wc, llo, koff);
    stage_step(sm[0], va, rowidx, kq4);
    pipe_barrier();
  }
  // step 30: compute sm[0], stage vb(=step 31)->sm[1]
  compute_step(sm[0], acc, wr, wc, llo, koff);
  stage_step(sm[1], vb, rowidx, kq4);
  pipe_barrier();
  // step 31: compute only
  compute_step(sm[1], acc, wr, wc, llo, koff);

  // epilogue: write partial gram
  // C/D layout (m89/m91 verified): col = lane&15, row = (lane>>4)*4 + reg
  if (atomic_mode) {
    float* out = outp + (size_t)b * GRAM;
    #pragma unroll
    for (int i = 0; i < 4; ++i) {
      int row0 = wr * 64 + i * 16 + lhi * 4;
      #pragma unroll
      for (int j = 0; j < 8; ++j) {
        int col = wc * 128 + j * 16 + llo;
        #pragma unroll
        for (int r = 0; r < 4; ++r)
          atomicAdd(&out[(size_t)(row0 + r) * MROWS + col], acc[i][j][r]);
      }
    }
  } else {
    float* out = outp + (size_t)bidx * GRAM;
    #pragma unroll
    for (int i = 0; i < 4; ++i) {
      int row0 = wr * 64 + i * 16 + lhi * 4;
      #pragma unroll
      for (int j = 0; j < 8; ++j) {
        int col = wc * 128 + j * 16 + llo;
        #pragma unroll
        for (int r = 0; r < 4; ++r)
          out[(size_t)(row0 + r) * MROWS + col] = acc[i][j][r];
      }
    }
  }
}

// One block per batch: inverse norms from gram diagonal (sum over nchunk slices)
__global__ __launch_bounds__(256) void norms_kernel(
    const float* __restrict__ gram, float* __restrict__ norms, int nchunk)
{
  int b = blockIdx.x;
  int d = threadIdx.x;  // 0..255
  float g = 0.f;
  for (int c = 0; c < nchunk; ++c)
    g += gram[(size_t)(b * nchunk + c) * GRAM + (size_t)d * (MROWS + 1)];
  float n = sqrtf(fmaxf(g, 0.f));
  n = fmaxf(n, 1e-12f);   // F.normalize eps
  norms[b * MROWS + d] = 1.0f / n;
}

// grid = BATCH*64; each block handles 1024 gram elements of one batch
__global__ __launch_bounds__(256) void loss_kernel(
    const float* __restrict__ gram, const float* __restrict__ norms,
    float* __restrict__ out, int nchunk)
{
  int b     = blockIdx.x >> 6;
  int strip = blockIdx.x & 63;
  int e0    = strip * 1024 + threadIdx.x * 4;
  const float* nb = norms + b * MROWS;

  f32x4 g = (f32x4){0.f, 0.f, 0.f, 0.f};
  for (int c = 0; c < nchunk; ++c) {
    f32x4 v = *(const f32x4*)(gram + (size_t)(b * nchunk + c) * GRAM + e0);
    g.x += v.x; g.y += v.y; g.z += v.z; g.w += v.w;
  }
  int i  = e0 >> 8;
  int j0 = e0 & 255;
  float ri = nb[i];
  float accl = 0.f;
  #pragma unroll
  for (int q = 0; q < 4; ++q) {
    int j = j0 + q;
    float gh = g[q] * ri * nb[j];
    // w_i*w_j: +1 within ss / tt blocks, -1 in st / ts blocks
    float sgn = ((i < CCH) == (j < CCH)) ? 1.f : -1.f;
    accl += sgn * gh * gh;
  }
  // block reduction
  #pragma unroll
  for (int off = 32; off > 0; off >>= 1)
    accl += __shfl_down(accl, off, 64);
  __shared__ float red[4];
  if ((threadIdx.x & 63) == 0) red[threadIdx.x >> 6] = accl;
  __syncthreads();
  if (threadIdx.x == 0) {
    float t = red[0] + red[1] + red[2] + red[3];
    atomicAdd(out, t * (1.0f / (float)(BATCH * CCH * CCH)));
  }
}

extern "C" void kernel_launch(void* const* d_in, const int* in_sizes, int n_in,
                              void* d_out, int out_size, void* d_ws, size_t ws_size,
                              hipStream_t stream) {
  const float* fs = (const float*)d_in[0];
  const float* ft = (const float*)d_in[1];
  float* out = (float*)d_out;
  float* wsf = (float*)d_ws;

  float* norms = wsf;            // 16*256 floats
  float* gram  = wsf + 4096;     // partials (64 MB) or accumulated gram (4 MB)

  const size_t need_partials = (size_t)(4096 + (size_t)BATCH * NCHUNK * GRAM) * 4;
  const int atomic_mode = (ws_size >= need_partials) ? 0 : 1;
  const int nchunk = atomic_mode ? 1 : NCHUNK;

  (void)hipMemsetAsync(d_out, 0, sizeof(float), stream);
  if (atomic_mode)
    (void)hipMemsetAsync(gram, 0, (size_t)BATCH * GRAM * sizeof(float), stream);

  gram_kernel<<<dim3(BATCH * NCHUNK), dim3(512), 0, stream>>>(fs, ft, gram, atomic_mode);
  norms_kernel<<<dim3(BATCH), dim3(256), 0, stream>>>(gram, norms, nchunk);
  loss_kernel<<<dim3(BATCH * 64), dim3(256), 0, stream>>>(gram, norms, out, nchunk);
}